// Round 1
// baseline (1096.633 us; speedup 1.0000x reference)
//
#include <hip/hip_runtime.h>
#include <hip/hip_bf16.h>

// MoE: T=8192 tokens, D=1024, F=4096, E=8, top-2.
// Pipeline: router(+x->bf16) -> prefix -> transpose w1/w2 -> gemm1(relu) -> gemm2(scatter-add)

typedef __bf16 bf16x8 __attribute__((ext_vector_type(8)));
typedef float  f32x4  __attribute__((ext_vector_type(4)));

__device__ __forceinline__ unsigned short f2bf(float f) {
    __hip_bfloat16 h = __float2bfloat16(f);
    return __builtin_bit_cast(unsigned short, h);
}

__device__ __forceinline__ void gload16(const unsigned short* g, unsigned short* l) {
    auto gp = (const __attribute__((address_space(1))) unsigned short*)g;
    auto lp = (__attribute__((address_space(3))) unsigned short*)l;
    __builtin_amdgcn_global_load_lds(gp, lp, 16, 0, 0);
}

// ---------------- router: logits (fp64 accum), top-2, softmax, compact lists; x -> bf16 ----------------
__global__ __launch_bounds__(256) void moe_router(
    const float* __restrict__ x, const float* __restrict__ rw, const float* __restrict__ rb,
    unsigned short* __restrict__ xb, int* __restrict__ counts,
    int* __restrict__ tokidx, float* __restrict__ gates)
{
    const int lane = threadIdx.x & 63;
    const int t = (blockIdx.x << 2) + (threadIdx.x >> 6);   // one wave per token

    double acc[8];
#pragma unroll
    for (int e = 0; e < 8; ++e) acc[e] = 0.0;
    float xv[16];
#pragma unroll
    for (int i = 0; i < 16; ++i) {
        const int d = lane + (i << 6);
        const float xd = x[(size_t)t * 1024 + d];
        xv[i] = xd;
        const float4 w0 = *(const float4*)(rw + d * 8);
        const float4 w1 = *(const float4*)(rw + d * 8 + 4);
        acc[0] += (double)xd * w0.x; acc[1] += (double)xd * w0.y;
        acc[2] += (double)xd * w0.z; acc[3] += (double)xd * w0.w;
        acc[4] += (double)xd * w1.x; acc[5] += (double)xd * w1.y;
        acc[6] += (double)xd * w1.z; acc[7] += (double)xd * w1.w;
    }
#pragma unroll
    for (int i = 0; i < 16; ++i)
        xb[(size_t)t * 1024 + lane + (i << 6)] = f2bf(xv[i]);

#pragma unroll
    for (int s = 0; s < 6; ++s) {
        const int off = 32 >> s;
#pragma unroll
        for (int e = 0; e < 8; ++e) acc[e] += __shfl_xor(acc[e], off, 64);
    }

    if (lane == 0) {
        float v[8];
#pragma unroll
        for (int e = 0; e < 8; ++e) v[e] = (float)acc[e] + rb[e];
        int i0 = 0;
#pragma unroll
        for (int e = 1; e < 8; ++e) if (v[e] > v[i0]) i0 = e;
        int i1 = (i0 == 0) ? 1 : 0;
#pragma unroll
        for (int e = 0; e < 8; ++e) if (e != i0 && v[e] > v[i1]) i1 = e;
        const float d = v[i1] - v[i0];          // <= 0
        const float ex = __expf(d);
        const float inv = 1.0f / (1.0f + ex);
        const int p0 = atomicAdd(&counts[i0], 1);
        tokidx[(i0 << 13) + p0] = t; gates[(i0 << 13) + p0] = inv;
        const int p1 = atomicAdd(&counts[i1], 1);
        tokidx[(i1 << 13) + p1] = t; gates[(i1 << 13) + p1] = ex * inv;
    }
}

__global__ void moe_prefix(const int* __restrict__ counts, int* __restrict__ prefix) {
    if (threadIdx.x == 0) {
        int s = 0;
        for (int e = 0; e < 8; ++e) { prefix[e] = s; s += counts[e]; }
    }
}

// ---------------- transpose+convert: src fp32 [E][R][C] -> dst bf16 [E][C][R] ----------------
__global__ __launch_bounds__(256) void transpose_convert(
    const float* __restrict__ src, unsigned short* __restrict__ dst, int R, int C)
{
    __shared__ float tile[64][65];
    const size_t eoff = (size_t)blockIdx.z * R * C;
    const float* s = src + eoff;
    unsigned short* d = dst + eoff;
    const int c0 = blockIdx.x << 6;
    const int r0 = blockIdx.y << 6;
    const int tr = threadIdx.x >> 4;
    const int tc = (threadIdx.x & 15) << 2;
#pragma unroll
    for (int p = 0; p < 4; ++p) {
        const int r = tr + (p << 4);
        const float4 v = *(const float4*)(s + (size_t)(r0 + r) * C + c0 + tc);
        tile[r][tc + 0] = v.x; tile[r][tc + 1] = v.y;
        tile[r][tc + 2] = v.z; tile[r][tc + 3] = v.w;
    }
    __syncthreads();
#pragma unroll
    for (int p = 0; p < 4; ++p) {
        const int c = tr + (p << 4);
        ushort4 o;
        o.x = f2bf(tile[tc + 0][c]);
        o.y = f2bf(tile[tc + 1][c]);
        o.z = f2bf(tile[tc + 2][c]);
        o.w = f2bf(tile[tc + 3][c]);
        *(ushort4*)(d + (size_t)(c0 + c) * R + r0 + tc) = o;
    }
}

// ---------------- GEMM1: h = relu(x[tok] @ w1[e] + b1[e]), bf16 out ----------------
__global__ __launch_bounds__(256, 2) void moe_gemm1(
    const unsigned short* __restrict__ xb,   // [8192][1024] bf16
    const unsigned short* __restrict__ w1T,  // [E][4096][1024] bf16 (N-major)
    const float* __restrict__ b1,            // [E][4096]
    const int* __restrict__ counts, const int* __restrict__ prefix,
    const int* __restrict__ tokidx,
    unsigned short* __restrict__ h)          // [16384][4096] bf16
{
    const int e = blockIdx.z;
    const int cnt = counts[e];
    const int m0 = blockIdx.y << 7;
    if (m0 >= cnt) return;
    const int n0 = blockIdx.x << 7;

    __shared__ __align__(16) unsigned short As[2][128 * 64];
    __shared__ __align__(16) unsigned short Bs[2][128 * 64];

    const int tid = threadIdx.x;
    const int lane = tid & 63;
    const int w = tid >> 6;
    const int lr = lane >> 3, ls = lane & 7;

    const unsigned short* abase[4];
    const unsigned short* bbase[4];
#pragma unroll
    for (int c = 0; c < 4; ++c) {
        const int row = (w << 5) + (c << 3) + lr;
        const int kg = ls ^ (row & 7);          // source pre-swizzle (linear LDS dest)
        int idx = m0 + row; if (idx > cnt - 1) idx = cnt - 1;
        const int tok = tokidx[(e << 13) + idx];
        abase[c] = xb + (size_t)tok * 1024 + (kg << 3);
        bbase[c] = w1T + ((size_t)e * 4096 + n0 + row) * 1024 + (kg << 3);
    }

    const int wm = (w >> 1) << 6;
    const int wn = (w & 1) << 6;

    {   // prologue stage
        unsigned short* Ad = &As[0][w << 11];
        unsigned short* Bd = &Bs[0][w << 11];
#pragma unroll
        for (int c = 0; c < 4; ++c) {
            gload16(abase[c], Ad + (c << 9));
            gload16(bbase[c], Bd + (c << 9));
        }
    }
    f32x4 acc[4][4];
#pragma unroll
    for (int m = 0; m < 4; ++m)
#pragma unroll
        for (int n = 0; n < 4; ++n) { acc[m][n][0]=0.f; acc[m][n][1]=0.f; acc[m][n][2]=0.f; acc[m][n][3]=0.f; }

    __syncthreads();

    const int nK = 1024 / 64;
    for (int kt = 0; kt < nK; ++kt) {
        const int cur = kt & 1;
        if (kt + 1 < nK) {
            unsigned short* Ad = &As[cur ^ 1][w << 11];
            unsigned short* Bd = &Bs[cur ^ 1][w << 11];
            const int ko = (kt + 1) << 6;
#pragma unroll
            for (int c = 0; c < 4; ++c) {
                gload16(abase[c] + ko, Ad + (c << 9));
                gload16(bbase[c] + ko, Bd + (c << 9));
            }
        }
        const unsigned short* A = As[cur];
        const unsigned short* B = Bs[cur];
#pragma unroll
        for (int ks = 0; ks < 2; ++ks) {
            const int slot = (ks << 2) + (lane >> 4);
            bf16x8 af[4], bfr[4];
#pragma unroll
            for (int m = 0; m < 4; ++m) {
                const int r = wm + (m << 4) + (lane & 15);
                af[m] = *(const bf16x8*)(A + (r << 6) + ((slot ^ (r & 7)) << 3));
            }
#pragma unroll
            for (int n = 0; n < 4; ++n) {
                const int r = wn + (n << 4) + (lane & 15);
                bfr[n] = *(const bf16x8*)(B + (r << 6) + ((slot ^ (r & 7)) << 3));
            }
#pragma unroll
            for (int m = 0; m < 4; ++m)
#pragma unroll
                for (int n = 0; n < 4; ++n)
                    acc[m][n] = __builtin_amdgcn_mfma_f32_16x16x32_bf16(af[m], bfr[n], acc[m][n], 0, 0, 0);
        }
        __syncthreads();
    }

    const int hb = prefix[e] + m0;
#pragma unroll
    for (int n = 0; n < 4; ++n) {
        const int bcol = n0 + wn + (n << 4) + (lane & 15);
        const float bias = b1[(e << 12) + bcol];
#pragma unroll
        for (int m = 0; m < 4; ++m) {
#pragma unroll
            for (int j = 0; j < 4; ++j) {
                const int r = wm + (m << 4) + ((lane >> 4) << 2) + j;
                if (m0 + r < cnt) {
                    float v = acc[m][n][j] + bias;
                    v = fmaxf(v, 0.0f);
                    h[(size_t)(hb + r) * 4096 + bcol] = f2bf(v);
                }
            }
        }
    }
}

// ---------------- GEMM2: out[tok] += gate * (h @ w2[e] + b2[e]) ----------------
__global__ __launch_bounds__(256, 2) void moe_gemm2(
    const unsigned short* __restrict__ h,    // [16384][4096] bf16
    const unsigned short* __restrict__ w2T,  // [E][1024][4096] bf16 (N-major)
    const float* __restrict__ b2,            // [E][1024]
    const int* __restrict__ counts, const int* __restrict__ prefix,
    const int* __restrict__ tokidx, const float* __restrict__ gates,
    float* __restrict__ out)                 // [8192][1024] fp32
{
    const int e = blockIdx.z;
    const int cnt = counts[e];
    const int m0 = blockIdx.y << 7;
    if (m0 >= cnt) return;
    const int n0 = blockIdx.x << 7;

    __shared__ __align__(16) unsigned short As[2][128 * 64];
    __shared__ __align__(16) unsigned short Bs[2][128 * 64];

    const int tid = threadIdx.x;
    const int lane = tid & 63;
    const int w = tid >> 6;
    const int lr = lane >> 3, ls = lane & 7;
    const int hb = prefix[e];

    const unsigned short* abase[4];
    const unsigned short* bbase[4];
#pragma unroll
    for (int c = 0; c < 4; ++c) {
        const int row = (w << 5) + (c << 3) + lr;
        const int kg = ls ^ (row & 7);
        int idx = m0 + row; if (idx > cnt - 1) idx = cnt - 1;
        abase[c] = h + (size_t)(hb + idx) * 4096 + (kg << 3);
        bbase[c] = w2T + ((size_t)e * 1024 + n0 + row) * 4096 + (kg << 3);
    }

    const int wm = (w >> 1) << 6;
    const int wn = (w & 1) << 6;

    {   // prologue stage
        unsigned short* Ad = &As[0][w << 11];
        unsigned short* Bd = &Bs[0][w << 11];
#pragma unroll
        for (int c = 0; c < 4; ++c) {
            gload16(abase[c], Ad + (c << 9));
            gload16(bbase[c], Bd + (c << 9));
        }
    }
    f32x4 acc[4][4];
#pragma unroll
    for (int m = 0; m < 4; ++m)
#pragma unroll
        for (int n = 0; n < 4; ++n) { acc[m][n][0]=0.f; acc[m][n][1]=0.f; acc[m][n][2]=0.f; acc[m][n][3]=0.f; }

    __syncthreads();

    const int nK = 4096 / 64;
    for (int kt = 0; kt < nK; ++kt) {
        const int cur = kt & 1;
        if (kt + 1 < nK) {
            unsigned short* Ad = &As[cur ^ 1][w << 11];
            unsigned short* Bd = &Bs[cur ^ 1][w << 11];
            const int ko = (kt + 1) << 6;
#pragma unroll
            for (int c = 0; c < 4; ++c) {
                gload16(abase[c] + ko, Ad + (c << 9));
                gload16(bbase[c] + ko, Bd + (c << 9));
            }
        }
        const unsigned short* A = As[cur];
        const unsigned short* B = Bs[cur];
#pragma unroll
        for (int ks = 0; ks < 2; ++ks) {
            const int slot = (ks << 2) + (lane >> 4);
            bf16x8 af[4], bfr[4];
#pragma unroll
            for (int m = 0; m < 4; ++m) {
                const int r = wm + (m << 4) + (lane & 15);
                af[m] = *(const bf16x8*)(A + (r << 6) + ((slot ^ (r & 7)) << 3));
            }
#pragma unroll
            for (int n = 0; n < 4; ++n) {
                const int r = wn + (n << 4) + (lane & 15);
                bfr[n] = *(const bf16x8*)(B + (r << 6) + ((slot ^ (r & 7)) << 3));
            }
#pragma unroll
            for (int m = 0; m < 4; ++m)
#pragma unroll
                for (int n = 0; n < 4; ++n)
                    acc[m][n] = __builtin_amdgcn_mfma_f32_16x16x32_bf16(af[m], bfr[n], acc[m][n], 0, 0, 0);
        }
        __syncthreads();
    }

    const int tseg = e << 13;
#pragma unroll
    for (int m = 0; m < 4; ++m) {
        int rows[4]; float gs[4]; int toks[4];
#pragma unroll
        for (int j = 0; j < 4; ++j) {
            const int r = wm + (m << 4) + ((lane >> 4) << 2) + j;
            rows[j] = m0 + r;
            int cl = rows[j]; if (cl > cnt - 1) cl = cnt - 1;
            toks[j] = tokidx[tseg + cl];
            gs[j] = gates[tseg + cl];
        }
#pragma unroll
        for (int n = 0; n < 4; ++n) {
            const int bcol = n0 + wn + (n << 4) + (lane & 15);
            const float bias = b2[(e << 10) + bcol];
#pragma unroll
            for (int j = 0; j < 4; ++j) {
                if (rows[j] < cnt) {
                    const float v = (acc[m][n][j] + bias) * gs[j];
                    atomicAdd(&out[(size_t)toks[j] * 1024 + bcol], v);
                }
            }
        }
    }
}

extern "C" void kernel_launch(void* const* d_in, const int* in_sizes, int n_in,
                              void* d_out, int out_size, void* d_ws, size_t ws_size,
                              hipStream_t stream)
{
    const float* x  = (const float*)d_in[0];
    const float* rw = (const float*)d_in[1];
    const float* rb = (const float*)d_in[2];
    const float* w1 = (const float*)d_in[3];
    const float* b1 = (const float*)d_in[4];
    const float* w2 = (const float*)d_in[5];
    const float* b2 = (const float*)d_in[6];
    float* out = (float*)d_out;

    char* ws = (char*)d_ws;
    size_t off = 0;
    auto alloc = [&](size_t bytes) -> void* {
        off = (off + 255) & ~(size_t)255;
        void* p = ws + off;
        off += bytes;
        return p;
    };
    int* counts = (int*)alloc(8 * 4);
    int* prefix = (int*)alloc(8 * 4);
    int* tokidx = (int*)alloc((size_t)8 * 8192 * 4);
    float* gates = (float*)alloc((size_t)8 * 8192 * 4);
    unsigned short* xb   = (unsigned short*)alloc((size_t)8192 * 1024 * 2);
    unsigned short* w1T  = (unsigned short*)alloc((size_t)8 * 4096 * 1024 * 2);
    unsigned short* w2T  = (unsigned short*)alloc((size_t)8 * 1024 * 4096 * 2);
    unsigned short* hbuf = (unsigned short*)alloc((size_t)16384 * 4096 * 2);
    if (off > ws_size) return;  // workspace too small: fail loudly via validation

    hipMemsetAsync(counts, 0, 64, stream);
    hipMemsetAsync(d_out, 0, (size_t)out_size * 4, stream);

    transpose_convert<<<dim3(64, 16, 8), 256, 0, stream>>>(w1, w1T, 1024, 4096);
    transpose_convert<<<dim3(16, 64, 8), 256, 0, stream>>>(w2, w2T, 4096, 1024);
    moe_router<<<2048, 256, 0, stream>>>(x, rw, rb, xb, counts, tokidx, gates);
    moe_prefix<<<1, 64, 0, stream>>>(counts, prefix);
    moe_gemm1<<<dim3(32, 64, 8), 256, 0, stream>>>(xb, w1T, b1, counts, prefix, tokidx, hbuf);
    moe_gemm2<<<dim3(8, 64, 8), 256, 0, stream>>>(hbuf, w2T, b2, counts, prefix, tokidx, gates, out);
}

// Round 5
// 1068.444 us; speedup vs baseline: 1.0264x; 1.0264x over previous
//
#include <hip/hip_runtime.h>
#include <hip/hip_bf16.h>

// MoE: T=8192 tokens, D=1024, F=4096, E=8, top-2.
// Pipeline: router(+x->bf16) -> prefix -> transpose w1/w2 -> gemm1(relu) -> gemm2(scatter-add)
// R1: expert-aligned XCD swizzle — e = blockIdx.x % 8 so all N-blocks of one
//     (expert, m-panel) land on the same XCD (linear%8 == e), giving L2 reuse
//     of the A-panel and expert-private weight streaming.
// R2/R3/R4: identical resubmits (benches lost to GPU-acquisition timeouts).

typedef __bf16 bf16x8 __attribute__((ext_vector_type(8)));
typedef float  f32x4  __attribute__((ext_vector_type(4)));

__device__ __forceinline__ unsigned short f2bf(float f) {
    __hip_bfloat16 h = __float2bfloat16(f);
    return __builtin_bit_cast(unsigned short, h);
}

__device__ __forceinline__ void gload16(const unsigned short* g, unsigned short* l) {
    auto gp = (const __attribute__((address_space(1))) unsigned short*)g;
    auto lp = (__attribute__((address_space(3))) unsigned short*)l;
    __builtin_amdgcn_global_load_lds(gp, lp, 16, 0, 0);
}

// ---------------- router: logits (fp64 accum), top-2, softmax, compact lists; x -> bf16 ----------------
__global__ __launch_bounds__(256) void moe_router(
    const float* __restrict__ x, const float* __restrict__ rw, const float* __restrict__ rb,
    unsigned short* __restrict__ xb, int* __restrict__ counts,
    int* __restrict__ tokidx, float* __restrict__ gates)
{
    const int lane = threadIdx.x & 63;
    const int t = (blockIdx.x << 2) + (threadIdx.x >> 6);   // one wave per token

    double acc[8];
#pragma unroll
    for (int e = 0; e < 8; ++e) acc[e] = 0.0;
    float xv[16];
#pragma unroll
    for (int i = 0; i < 16; ++i) {
        const int d = lane + (i << 6);
        const float xd = x[(size_t)t * 1024 + d];
        xv[i] = xd;
        const float4 w0 = *(const float4*)(rw + d * 8);
        const float4 w1 = *(const float4*)(rw + d * 8 + 4);
        acc[0] += (double)xd * w0.x; acc[1] += (double)xd * w0.y;
        acc[2] += (double)xd * w0.z; acc[3] += (double)xd * w0.w;
        acc[4] += (double)xd * w1.x; acc[5] += (double)xd * w1.y;
        acc[6] += (double)xd * w1.z; acc[7] += (double)xd * w1.w;
    }
#pragma unroll
    for (int i = 0; i < 16; ++i)
        xb[(size_t)t * 1024 + lane + (i << 6)] = f2bf(xv[i]);

#pragma unroll
    for (int s = 0; s < 6; ++s) {
        const int off = 32 >> s;
#pragma unroll
        for (int e = 0; e < 8; ++e) acc[e] += __shfl_xor(acc[e], off, 64);
    }

    if (lane == 0) {
        float v[8];
#pragma unroll
        for (int e = 0; e < 8; ++e) v[e] = (float)acc[e] + rb[e];
        int i0 = 0;
#pragma unroll
        for (int e = 1; e < 8; ++e) if (v[e] > v[i0]) i0 = e;
        int i1 = (i0 == 0) ? 1 : 0;
#pragma unroll
        for (int e = 0; e < 8; ++e) if (e != i0 && v[e] > v[i1]) i1 = e;
        const float d = v[i1] - v[i0];          // <= 0
        const float ex = __expf(d);
        const float inv = 1.0f / (1.0f + ex);
        const int p0 = atomicAdd(&counts[i0], 1);
        tokidx[(i0 << 13) + p0] = t; gates[(i0 << 13) + p0] = inv;
        const int p1 = atomicAdd(&counts[i1], 1);
        tokidx[(i1 << 13) + p1] = t; gates[(i1 << 13) + p1] = ex * inv;
    }
}

__global__ void moe_prefix(const int* __restrict__ counts, int* __restrict__ prefix) {
    if (threadIdx.x == 0) {
        int s = 0;
        for (int e = 0; e < 8; ++e) { prefix[e] = s; s += counts[e]; }
    }
}

// ---------------- transpose+convert: src fp32 [E][R][C] -> dst bf16 [E][C][R] ----------------
__global__ __launch_bounds__(256) void transpose_convert(
    const float* __restrict__ src, unsigned short* __restrict__ dst, int R, int C)
{
    __shared__ float tile[64][65];
    const size_t eoff = (size_t)blockIdx.z * R * C;
    const float* s = src + eoff;
    unsigned short* d = dst + eoff;
    const int c0 = blockIdx.x << 6;
    const int r0 = blockIdx.y << 6;
    const int tr = threadIdx.x >> 4;
    const int tc = (threadIdx.x & 15) << 2;
#pragma unroll
    for (int p = 0; p < 4; ++p) {
        const int r = tr + (p << 4);
        const float4 v = *(const float4*)(s + (size_t)(r0 + r) * C + c0 + tc);
        tile[r][tc + 0] = v.x; tile[r][tc + 1] = v.y;
        tile[r][tc + 2] = v.z; tile[r][tc + 3] = v.w;
    }
    __syncthreads();
#pragma unroll
    for (int p = 0; p < 4; ++p) {
        const int c = tr + (p << 4);
        ushort4 o;
        o.x = f2bf(tile[tc + 0][c]);
        o.y = f2bf(tile[tc + 1][c]);
        o.z = f2bf(tile[tc + 2][c]);
        o.w = f2bf(tile[tc + 3][c]);
        *(ushort4*)(d + (size_t)(c0 + c) * R + r0 + tc) = o;
    }
}

// ---------------- GEMM1: h = relu(x[tok] @ w1[e] + b1[e]), bf16 out ----------------
// grid: x = 8 experts * 32 nblocks (e = x&7 -> XCD-aligned), y = 64 m-blocks
__global__ __launch_bounds__(256, 2) void moe_gemm1(
    const unsigned short* __restrict__ xb,   // [8192][1024] bf16
    const unsigned short* __restrict__ w1T,  // [E][4096][1024] bf16 (N-major)
    const float* __restrict__ b1,            // [E][4096]
    const int* __restrict__ counts, const int* __restrict__ prefix,
    const int* __restrict__ tokidx,
    unsigned short* __restrict__ h)          // [16384][4096] bf16
{
    const int e = blockIdx.x & 7;
    const int cnt = counts[e];
    const int m0 = blockIdx.y << 7;
    if (m0 >= cnt) return;
    const int n0 = (blockIdx.x >> 3) << 7;

    __shared__ __align__(16) unsigned short As[2][128 * 64];
    __shared__ __align__(16) unsigned short Bs[2][128 * 64];

    const int tid = threadIdx.x;
    const int lane = tid & 63;
    const int w = tid >> 6;
    const int lr = lane >> 3, ls = lane & 7;

    const unsigned short* abase[4];
    const unsigned short* bbase[4];
#pragma unroll
    for (int c = 0; c < 4; ++c) {
        const int row = (w << 5) + (c << 3) + lr;
        const int kg = ls ^ (row & 7);          // source pre-swizzle (linear LDS dest)
        int idx = m0 + row; if (idx > cnt - 1) idx = cnt - 1;
        const int tok = tokidx[(e << 13) + idx];
        abase[c] = xb + (size_t)tok * 1024 + (kg << 3);
        bbase[c] = w1T + ((size_t)e * 4096 + n0 + row) * 1024 + (kg << 3);
    }

    const int wm = (w >> 1) << 6;
    const int wn = (w & 1) << 6;

    {   // prologue stage
        unsigned short* Ad = &As[0][w << 11];
        unsigned short* Bd = &Bs[0][w << 11];
#pragma unroll
        for (int c = 0; c < 4; ++c) {
            gload16(abase[c], Ad + (c << 9));
            gload16(bbase[c], Bd + (c << 9));
        }
    }
    f32x4 acc[4][4];
#pragma unroll
    for (int m = 0; m < 4; ++m)
#pragma unroll
        for (int n = 0; n < 4; ++n) { acc[m][n][0]=0.f; acc[m][n][1]=0.f; acc[m][n][2]=0.f; acc[m][n][3]=0.f; }

    __syncthreads();

    const int nK = 1024 / 64;
    for (int kt = 0; kt < nK; ++kt) {
        const int cur = kt & 1;
        if (kt + 1 < nK) {
            unsigned short* Ad = &As[cur ^ 1][w << 11];
            unsigned short* Bd = &Bs[cur ^ 1][w << 11];
            const int ko = (kt + 1) << 6;
#pragma unroll
            for (int c = 0; c < 4; ++c) {
                gload16(abase[c] + ko, Ad + (c << 9));
                gload16(bbase[c] + ko, Bd + (c << 9));
            }
        }
        const unsigned short* A = As[cur];
        const unsigned short* B = Bs[cur];
#pragma unroll
        for (int ks = 0; ks < 2; ++ks) {
            const int slot = (ks << 2) + (lane >> 4);
            bf16x8 af[4], bfr[4];
#pragma unroll
            for (int m = 0; m < 4; ++m) {
                const int r = wm + (m << 4) + (lane & 15);
                af[m] = *(const bf16x8*)(A + (r << 6) + ((slot ^ (r & 7)) << 3));
            }
#pragma unroll
            for (int n = 0; n < 4; ++n) {
                const int r = wn + (n << 4) + (lane & 15);
                bfr[n] = *(const bf16x8*)(B + (r << 6) + ((slot ^ (r & 7)) << 3));
            }
#pragma unroll
            for (int m = 0; m < 4; ++m)
#pragma unroll
                for (int n = 0; n < 4; ++n)
                    acc[m][n] = __builtin_amdgcn_mfma_f32_16x16x32_bf16(af[m], bfr[n], acc[m][n], 0, 0, 0);
        }
        __syncthreads();
    }

    const int hb = prefix[e] + m0;
#pragma unroll
    for (int n = 0; n < 4; ++n) {
        const int bcol = n0 + wn + (n << 4) + (lane & 15);
        const float bias = b1[(e << 12) + bcol];
#pragma unroll
        for (int m = 0; m < 4; ++m) {
#pragma unroll
            for (int j = 0; j < 4; ++j) {
                const int r = wm + (m << 4) + ((lane >> 4) << 2) + j;
                if (m0 + r < cnt) {
                    float v = acc[m][n][j] + bias;
                    v = fmaxf(v, 0.0f);
                    h[(size_t)(hb + r) * 4096 + bcol] = f2bf(v);
                }
            }
        }
    }
}

// ---------------- GEMM2: out[tok] += gate * (h @ w2[e] + b2[e]) ----------------
// grid: x = 8 experts * 8 nblocks (e = x&7 -> XCD-aligned), y = 64 m-blocks
__global__ __launch_bounds__(256, 2) void moe_gemm2(
    const unsigned short* __restrict__ h,    // [16384][4096] bf16
    const unsigned short* __restrict__ w2T,  // [E][1024][4096] bf16 (N-major)
    const float* __restrict__ b2,            // [E][1024]
    const int* __restrict__ counts, const int* __restrict__ prefix,
    const int* __restrict__ tokidx, const float* __restrict__ gates,
    float* __restrict__ out)                 // [8192][1024] fp32
{
    const int e = blockIdx.x & 7;
    const int cnt = counts[e];
    const int m0 = blockIdx.y << 7;
    if (m0 >= cnt) return;
    const int n0 = (blockIdx.x >> 3) << 7;

    __shared__ __align__(16) unsigned short As[2][128 * 64];
    __shared__ __align__(16) unsigned short Bs[2][128 * 64];

    const int tid = threadIdx.x;
    const int lane = tid & 63;
    const int w = tid >> 6;
    const int lr = lane >> 3, ls = lane & 7;
    const int hb = prefix[e];

    const unsigned short* abase[4];
    const unsigned short* bbase[4];
#pragma unroll
    for (int c = 0; c < 4; ++c) {
        const int row = (w << 5) + (c << 3) + lr;
        const int kg = ls ^ (row & 7);
        int idx = m0 + row; if (idx > cnt - 1) idx = cnt - 1;
        abase[c] = h + (size_t)(hb + idx) * 4096 + (kg << 3);
        bbase[c] = w2T + ((size_t)e * 1024 + n0 + row) * 4096 + (kg << 3);
    }

    const int wm = (w >> 1) << 6;
    const int wn = (w & 1) << 6;

    {   // prologue stage
        unsigned short* Ad = &As[0][w << 11];
        unsigned short* Bd = &Bs[0][w << 11];
#pragma unroll
        for (int c = 0; c < 4; ++c) {
            gload16(abase[c], Ad + (c << 9));
            gload16(bbase[c], Bd + (c << 9));
        }
    }
    f32x4 acc[4][4];
#pragma unroll
    for (int m = 0; m < 4; ++m)
#pragma unroll
        for (int n = 0; n < 4; ++n) { acc[m][n][0]=0.f; acc[m][n][1]=0.f; acc[m][n][2]=0.f; acc[m][n][3]=0.f; }

    __syncthreads();

    const int nK = 4096 / 64;
    for (int kt = 0; kt < nK; ++kt) {
        const int cur = kt & 1;
        if (kt + 1 < nK) {
            unsigned short* Ad = &As[cur ^ 1][w << 11];
            unsigned short* Bd = &Bs[cur ^ 1][w << 11];
            const int ko = (kt + 1) << 6;
#pragma unroll
            for (int c = 0; c < 4; ++c) {
                gload16(abase[c] + ko, Ad + (c << 9));
                gload16(bbase[c] + ko, Bd + (c << 9));
            }
        }
        const unsigned short* A = As[cur];
        const unsigned short* B = Bs[cur];
#pragma unroll
        for (int ks = 0; ks < 2; ++ks) {
            const int slot = (ks << 2) + (lane >> 4);
            bf16x8 af[4], bfr[4];
#pragma unroll
            for (int m = 0; m < 4; ++m) {
                const int r = wm + (m << 4) + (lane & 15);
                af[m] = *(const bf16x8*)(A + (r << 6) + ((slot ^ (r & 7)) << 3));
            }
#pragma unroll
            for (int n = 0; n < 4; ++n) {
                const int r = wn + (n << 4) + (lane & 15);
                bfr[n] = *(const bf16x8*)(B + (r << 6) + ((slot ^ (r & 7)) << 3));
            }
#pragma unroll
            for (int m = 0; m < 4; ++m)
#pragma unroll
                for (int n = 0; n < 4; ++n)
                    acc[m][n] = __builtin_amdgcn_mfma_f32_16x16x32_bf16(af[m], bfr[n], acc[m][n], 0, 0, 0);
        }
        __syncthreads();
    }

    const int tseg = e << 13;
#pragma unroll
    for (int m = 0; m < 4; ++m) {
        int rows[4]; float gs[4]; int toks[4];
#pragma unroll
        for (int j = 0; j < 4; ++j) {
            const int r = wm + (m << 4) + ((lane >> 4) << 2) + j;
            rows[j] = m0 + r;
            int cl = rows[j]; if (cl > cnt - 1) cl = cnt - 1;
            toks[j] = tokidx[tseg + cl];
            gs[j] = gates[tseg + cl];
        }
#pragma unroll
        for (int n = 0; n < 4; ++n) {
            const int bcol = n0 + wn + (n << 4) + (lane & 15);
            const float bias = b2[(e << 10) + bcol];
#pragma unroll
            for (int j = 0; j < 4; ++j) {
                if (rows[j] < cnt) {
                    const float v = (acc[m][n][j] + bias) * gs[j];
                    atomicAdd(&out[(size_t)toks[j] * 1024 + bcol], v);
                }
            }
        }
    }
}

extern "C" void kernel_launch(void* const* d_in, const int* in_sizes, int n_in,
                              void* d_out, int out_size, void* d_ws, size_t ws_size,
                              hipStream_t stream)
{
    const float* x  = (const float*)d_in[0];
    const float* rw = (const float*)d_in[1];
    const float* rb = (const float*)d_in[2];
    const float* w1 = (const float*)d_in[3];
    const float* b1 = (const float*)d_in[4];
    const float* w2 = (const float*)d_in[5];
    const float* b2 = (const float*)d_in[6];
    float* out = (float*)d_out;

    char* ws = (char*)d_ws;
    size_t off = 0;
    auto alloc = [&](size_t bytes) -> void* {
        off = (off + 255) & ~(size_t)255;
        void* p = ws + off;
        off += bytes;
        return p;
    };
    int* counts = (int*)alloc(8 * 4);
    int* prefix = (int*)alloc(8 * 4);
    int* tokidx = (int*)alloc((size_t)8 * 8192 * 4);
    float* gates = (float*)alloc((size_t)8 * 8192 * 4);
    unsigned short* xb   = (unsigned short*)alloc((size_t)8192 * 1024 * 2);
    unsigned short* w1T  = (unsigned short*)alloc((size_t)8 * 4096 * 1024 * 2);
    unsigned short* w2T  = (unsigned short*)alloc((size_t)8 * 1024 * 4096 * 2);
    unsigned short* hbuf = (unsigned short*)alloc((size_t)16384 * 4096 * 2);
    if (off > ws_size) return;  // workspace too small: fail loudly via validation

    hipMemsetAsync(counts, 0, 64, stream);
    hipMemsetAsync(d_out, 0, (size_t)out_size * 4, stream);

    transpose_convert<<<dim3(64, 16, 8), 256, 0, stream>>>(w1, w1T, 1024, 4096);
    transpose_convert<<<dim3(16, 64, 8), 256, 0, stream>>>(w2, w2T, 4096, 1024);
    moe_router<<<2048, 256, 0, stream>>>(x, rw, rb, xb, counts, tokidx, gates);
    moe_prefix<<<1, 64, 0, stream>>>(counts, prefix);
    moe_gemm1<<<dim3(256, 64, 1), 256, 0, stream>>>(xb, w1T, b1, counts, prefix, tokidx, hbuf);
    moe_gemm2<<<dim3(64, 64, 1), 256, 0, stream>>>(hbuf, w2T, b2, counts, prefix, tokidx, gates, out);
}

// Round 8
// 950.932 us; speedup vs baseline: 1.1532x; 1.1236x over previous
//
#include <hip/hip_runtime.h>
#include <hip/hip_bf16.h>

// MoE: T=8192 tokens, D=1024, F=4096, E=8, top-2.
// Pipeline: router(+x->bf16) -> prefix -> transpose w1/w2 -> gemm1(relu) -> gemm2(scatter-add)
// R1: expert-aligned XCD swizzle (e = blockIdx.x & 7) — FETCH 566->148 MB (verified R5).
// R5: single-buffered 32KB LDS per GEMM (m97 structure). The explicit 64KB
//     double-buffer capped occupancy at 2 blocks/CU (m132 signature: ~500 TF);
//     single-buffer + __launch_bounds__(256,4) restores 3-4 blocks/CU.
// R6/R7: identical resubmits (benches lost to GPU-acquisition timeouts).

typedef __bf16 bf16x8 __attribute__((ext_vector_type(8)));
typedef float  f32x4  __attribute__((ext_vector_type(4)));

__device__ __forceinline__ unsigned short f2bf(float f) {
    __hip_bfloat16 h = __float2bfloat16(f);
    return __builtin_bit_cast(unsigned short, h);
}

__device__ __forceinline__ void gload16(const unsigned short* g, unsigned short* l) {
    auto gp = (const __attribute__((address_space(1))) unsigned short*)g;
    auto lp = (__attribute__((address_space(3))) unsigned short*)l;
    __builtin_amdgcn_global_load_lds(gp, lp, 16, 0, 0);
}

// ---------------- router: logits (fp64 accum), top-2, softmax, compact lists; x -> bf16 ----------------
__global__ __launch_bounds__(256) void moe_router(
    const float* __restrict__ x, const float* __restrict__ rw, const float* __restrict__ rb,
    unsigned short* __restrict__ xb, int* __restrict__ counts,
    int* __restrict__ tokidx, float* __restrict__ gates)
{
    const int lane = threadIdx.x & 63;
    const int t = (blockIdx.x << 2) + (threadIdx.x >> 6);   // one wave per token

    double acc[8];
#pragma unroll
    for (int e = 0; e < 8; ++e) acc[e] = 0.0;
    float xv[16];
#pragma unroll
    for (int i = 0; i < 16; ++i) {
        const int d = lane + (i << 6);
        const float xd = x[(size_t)t * 1024 + d];
        xv[i] = xd;
        const float4 w0 = *(const float4*)(rw + d * 8);
        const float4 w1 = *(const float4*)(rw + d * 8 + 4);
        acc[0] += (double)xd * w0.x; acc[1] += (double)xd * w0.y;
        acc[2] += (double)xd * w0.z; acc[3] += (double)xd * w0.w;
        acc[4] += (double)xd * w1.x; acc[5] += (double)xd * w1.y;
        acc[6] += (double)xd * w1.z; acc[7] += (double)xd * w1.w;
    }
#pragma unroll
    for (int i = 0; i < 16; ++i)
        xb[(size_t)t * 1024 + lane + (i << 6)] = f2bf(xv[i]);

#pragma unroll
    for (int s = 0; s < 6; ++s) {
        const int off = 32 >> s;
#pragma unroll
        for (int e = 0; e < 8; ++e) acc[e] += __shfl_xor(acc[e], off, 64);
    }

    if (lane == 0) {
        float v[8];
#pragma unroll
        for (int e = 0; e < 8; ++e) v[e] = (float)acc[e] + rb[e];
        int i0 = 0;
#pragma unroll
        for (int e = 1; e < 8; ++e) if (v[e] > v[i0]) i0 = e;
        int i1 = (i0 == 0) ? 1 : 0;
#pragma unroll
        for (int e = 0; e < 8; ++e) if (e != i0 && v[e] > v[i1]) i1 = e;
        const float d = v[i1] - v[i0];          // <= 0
        const float ex = __expf(d);
        const float inv = 1.0f / (1.0f + ex);
        const int p0 = atomicAdd(&counts[i0], 1);
        tokidx[(i0 << 13) + p0] = t; gates[(i0 << 13) + p0] = inv;
        const int p1 = atomicAdd(&counts[i1], 1);
        tokidx[(i1 << 13) + p1] = t; gates[(i1 << 13) + p1] = ex * inv;
    }
}

__global__ void moe_prefix(const int* __restrict__ counts, int* __restrict__ prefix) {
    if (threadIdx.x == 0) {
        int s = 0;
        for (int e = 0; e < 8; ++e) { prefix[e] = s; s += counts[e]; }
    }
}

// ---------------- transpose+convert: src fp32 [E][R][C] -> dst bf16 [E][C][R] ----------------
__global__ __launch_bounds__(256) void transpose_convert(
    const float* __restrict__ src, unsigned short* __restrict__ dst, int R, int C)
{
    __shared__ float tile[64][65];
    const size_t eoff = (size_t)blockIdx.z * R * C;
    const float* s = src + eoff;
    unsigned short* d = dst + eoff;
    const int c0 = blockIdx.x << 6;
    const int r0 = blockIdx.y << 6;
    const int tr = threadIdx.x >> 4;
    const int tc = (threadIdx.x & 15) << 2;
#pragma unroll
    for (int p = 0; p < 4; ++p) {
        const int r = tr + (p << 4);
        const float4 v = *(const float4*)(s + (size_t)(r0 + r) * C + c0 + tc);
        tile[r][tc + 0] = v.x; tile[r][tc + 1] = v.y;
        tile[r][tc + 2] = v.z; tile[r][tc + 3] = v.w;
    }
    __syncthreads();
#pragma unroll
    for (int p = 0; p < 4; ++p) {
        const int c = tr + (p << 4);
        ushort4 o;
        o.x = f2bf(tile[tc + 0][c]);
        o.y = f2bf(tile[tc + 1][c]);
        o.z = f2bf(tile[tc + 2][c]);
        o.w = f2bf(tile[tc + 3][c]);
        *(ushort4*)(d + (size_t)(c0 + c) * R + r0 + tc) = o;
    }
}

// ---------------- GEMM1: h = relu(x[tok] @ w1[e] + b1[e]), bf16 out ----------------
// grid: x = 8 experts * 32 nblocks (e = x&7 -> XCD-aligned), y = 64 m-blocks
__global__ __launch_bounds__(256, 4) void moe_gemm1(
    const unsigned short* __restrict__ xb,   // [8192][1024] bf16
    const unsigned short* __restrict__ w1T,  // [E][4096][1024] bf16 (N-major)
    const float* __restrict__ b1,            // [E][4096]
    const int* __restrict__ counts, const int* __restrict__ prefix,
    const int* __restrict__ tokidx,
    unsigned short* __restrict__ h)          // [16384][4096] bf16
{
    const int e = blockIdx.x & 7;
    const int cnt = counts[e];
    const int m0 = blockIdx.y << 7;
    if (m0 >= cnt) return;
    const int n0 = (blockIdx.x >> 3) << 7;

    __shared__ __align__(16) unsigned short As[128 * 64];
    __shared__ __align__(16) unsigned short Bs[128 * 64];

    const int tid = threadIdx.x;
    const int lane = tid & 63;
    const int w = tid >> 6;
    const int lr = lane >> 3, ls = lane & 7;

    const unsigned short* abase[4];
    const unsigned short* bbase[4];
#pragma unroll
    for (int c = 0; c < 4; ++c) {
        const int row = (w << 5) + (c << 3) + lr;
        const int kg = ls ^ (row & 7);          // source pre-swizzle (linear LDS dest)
        int idx = m0 + row; if (idx > cnt - 1) idx = cnt - 1;
        const int tok = tokidx[(e << 13) + idx];
        abase[c] = xb + (size_t)tok * 1024 + (kg << 3);
        bbase[c] = w1T + ((size_t)e * 4096 + n0 + row) * 1024 + (kg << 3);
    }

    const int wm = (w >> 1) << 6;
    const int wn = (w & 1) << 6;

    f32x4 acc[4][4];
#pragma unroll
    for (int m = 0; m < 4; ++m)
#pragma unroll
        for (int n = 0; n < 4; ++n) { acc[m][n][0]=0.f; acc[m][n][1]=0.f; acc[m][n][2]=0.f; acc[m][n][3]=0.f; }

    const int nK = 1024 / 64;
    for (int kt = 0; kt < nK; ++kt) {
        unsigned short* Ad = &As[w << 11];
        unsigned short* Bd = &Bs[w << 11];
        const int ko = kt << 6;
#pragma unroll
        for (int c = 0; c < 4; ++c) {
            gload16(abase[c] + ko, Ad + (c << 9));
            gload16(bbase[c] + ko, Bd + (c << 9));
        }
        __syncthreads();        // drains vmcnt(0): tile resident
#pragma unroll
        for (int ks = 0; ks < 2; ++ks) {
            const int slot = (ks << 2) + (lane >> 4);
            bf16x8 af[4], bfr[4];
#pragma unroll
            for (int m = 0; m < 4; ++m) {
                const int r = wm + (m << 4) + (lane & 15);
                af[m] = *(const bf16x8*)(As + (r << 6) + ((slot ^ (r & 7)) << 3));
            }
#pragma unroll
            for (int n = 0; n < 4; ++n) {
                const int r = wn + (n << 4) + (lane & 15);
                bfr[n] = *(const bf16x8*)(Bs + (r << 6) + ((slot ^ (r & 7)) << 3));
            }
#pragma unroll
            for (int m = 0; m < 4; ++m)
#pragma unroll
                for (int n = 0; n < 4; ++n)
                    acc[m][n] = __builtin_amdgcn_mfma_f32_16x16x32_bf16(af[m], bfr[n], acc[m][n], 0, 0, 0);
        }
        __syncthreads();        // all waves done reading before next stage
    }

    const int hb = prefix[e] + m0;
#pragma unroll
    for (int n = 0; n < 4; ++n) {
        const int bcol = n0 + wn + (n << 4) + (lane & 15);
        const float bias = b1[(e << 12) + bcol];
#pragma unroll
        for (int m = 0; m < 4; ++m) {
#pragma unroll
            for (int j = 0; j < 4; ++j) {
                const int r = wm + (m << 4) + ((lane >> 4) << 2) + j;
                if (m0 + r < cnt) {
                    float v = acc[m][n][j] + bias;
                    v = fmaxf(v, 0.0f);
                    h[(size_t)(hb + r) * 4096 + bcol] = f2bf(v);
                }
            }
        }
    }
}

// ---------------- GEMM2: out[tok] += gate * (h @ w2[e] + b2[e]) ----------------
// grid: x = 8 experts * 8 nblocks (e = x&7 -> XCD-aligned), y = 64 m-blocks
__global__ __launch_bounds__(256, 4) void moe_gemm2(
    const unsigned short* __restrict__ h,    // [16384][4096] bf16
    const unsigned short* __restrict__ w2T,  // [E][1024][4096] bf16 (N-major)
    const float* __restrict__ b2,            // [E][1024]
    const int* __restrict__ counts, const int* __restrict__ prefix,
    const int* __restrict__ tokidx, const float* __restrict__ gates,
    float* __restrict__ out)                 // [8192][1024] fp32
{
    const int e = blockIdx.x & 7;
    const int cnt = counts[e];
    const int m0 = blockIdx.y << 7;
    if (m0 >= cnt) return;
    const int n0 = (blockIdx.x >> 3) << 7;

    __shared__ __align__(16) unsigned short As[128 * 64];
    __shared__ __align__(16) unsigned short Bs[128 * 64];

    const int tid = threadIdx.x;
    const int lane = tid & 63;
    const int w = tid >> 6;
    const int lr = lane >> 3, ls = lane & 7;
    const int hb = prefix[e];

    const unsigned short* abase[4];
    const unsigned short* bbase[4];
#pragma unroll
    for (int c = 0; c < 4; ++c) {
        const int row = (w << 5) + (c << 3) + lr;
        const int kg = ls ^ (row & 7);
        int idx = m0 + row; if (idx > cnt - 1) idx = cnt - 1;
        abase[c] = h + (size_t)(hb + idx) * 4096 + (kg << 3);
        bbase[c] = w2T + ((size_t)e * 1024 + n0 + row) * 4096 + (kg << 3);
    }

    const int wm = (w >> 1) << 6;
    const int wn = (w & 1) << 6;

    f32x4 acc[4][4];
#pragma unroll
    for (int m = 0; m < 4; ++m)
#pragma unroll
        for (int n = 0; n < 4; ++n) { acc[m][n][0]=0.f; acc[m][n][1]=0.f; acc[m][n][2]=0.f; acc[m][n][3]=0.f; }

    const int nK = 4096 / 64;
    for (int kt = 0; kt < nK; ++kt) {
        unsigned short* Ad = &As[w << 11];
        unsigned short* Bd = &Bs[w << 11];
        const int ko = kt << 6;
#pragma unroll
        for (int c = 0; c < 4; ++c) {
            gload16(abase[c] + ko, Ad + (c << 9));
            gload16(bbase[c] + ko, Bd + (c << 9));
        }
        __syncthreads();
#pragma unroll
        for (int ks = 0; ks < 2; ++ks) {
            const int slot = (ks << 2) + (lane >> 4);
            bf16x8 af[4], bfr[4];
#pragma unroll
            for (int m = 0; m < 4; ++m) {
                const int r = wm + (m << 4) + (lane & 15);
                af[m] = *(const bf16x8*)(As + (r << 6) + ((slot ^ (r & 7)) << 3));
            }
#pragma unroll
            for (int n = 0; n < 4; ++n) {
                const int r = wn + (n << 4) + (lane & 15);
                bfr[n] = *(const bf16x8*)(Bs + (r << 6) + ((slot ^ (r & 7)) << 3));
            }
#pragma unroll
            for (int m = 0; m < 4; ++m)
#pragma unroll
                for (int n = 0; n < 4; ++n)
                    acc[m][n] = __builtin_amdgcn_mfma_f32_16x16x32_bf16(af[m], bfr[n], acc[m][n], 0, 0, 0);
        }
        __syncthreads();
    }

    const int tseg = e << 13;
#pragma unroll
    for (int m = 0; m < 4; ++m) {
        int rows[4]; float gs[4]; int toks[4];
#pragma unroll
        for (int j = 0; j < 4; ++j) {
            const int r = wm + (m << 4) + ((lane >> 4) << 2) + j;
            rows[j] = m0 + r;
            int cl = rows[j]; if (cl > cnt - 1) cl = cnt - 1;
            toks[j] = tokidx[tseg + cl];
            gs[j] = gates[tseg + cl];
        }
#pragma unroll
        for (int n = 0; n < 4; ++n) {
            const int bcol = n0 + wn + (n << 4) + (lane & 15);
            const float bias = b2[(e << 10) + bcol];
#pragma unroll
            for (int j = 0; j < 4; ++j) {
                if (rows[j] < cnt) {
                    const float v = (acc[m][n][j] + bias) * gs[j];
                    atomicAdd(&out[(size_t)toks[j] * 1024 + bcol], v);
                }
            }
        }
    }
}

extern "C" void kernel_launch(void* const* d_in, const int* in_sizes, int n_in,
                              void* d_out, int out_size, void* d_ws, size_t ws_size,
                              hipStream_t stream)
{
    const float* x  = (const float*)d_in[0];
    const float* rw = (const float*)d_in[1];
    const float* rb = (const float*)d_in[2];
    const float* w1 = (const float*)d_in[3];
    const float* b1 = (const float*)d_in[4];
    const float* w2 = (const float*)d_in[5];
    const float* b2 = (const float*)d_in[6];
    float* out = (float*)d_out;

    char* ws = (char*)d_ws;
    size_t off = 0;
    auto alloc = [&](size_t bytes) -> void* {
        off = (off + 255) & ~(size_t)255;
        void* p = ws + off;
        off += bytes;
        return p;
    };
    int* counts = (int*)alloc(8 * 4);
    int* prefix = (int*)alloc(8 * 4);
    int* tokidx = (int*)alloc((size_t)8 * 8192 * 4);
    float* gates = (float*)alloc((size_t)8 * 8192 * 4);
    unsigned short* xb   = (unsigned short*)alloc((size_t)8192 * 1024 * 2);
    unsigned short* w1T  = (unsigned short*)alloc((size_t)8 * 4096 * 1024 * 2);
    unsigned short* w2T  = (unsigned short*)alloc((size_t)8 * 1024 * 4096 * 2);
    unsigned short* hbuf = (unsigned short*)alloc((size_t)16384 * 4096 * 2);
    if (off > ws_size) return;  // workspace too small: fail loudly via validation

    hipMemsetAsync(counts, 0, 64, stream);
    hipMemsetAsync(d_out, 0, (size_t)out_size * 4, stream);

    transpose_convert<<<dim3(64, 16, 8), 256, 0, stream>>>(w1, w1T, 1024, 4096);
    transpose_convert<<<dim3(16, 64, 8), 256, 0, stream>>>(w2, w2T, 4096, 1024);
    moe_router<<<2048, 256, 0, stream>>>(x, rw, rb, xb, counts, tokidx, gates);
    moe_prefix<<<1, 64, 0, stream>>>(counts, prefix);
    moe_gemm1<<<dim3(256, 64, 1), 256, 0, stream>>>(xb, w1T, b1, counts, prefix, tokidx, hbuf);
    moe_gemm2<<<dim3(64, 64, 1), 256, 0, stream>>>(hbuf, w2T, b2, counts, prefix, tokidx, gates, out);
}